// Round 7
// baseline (127.435 us; speedup 1.0000x reference)
//
#include <hip/hip_runtime.h>
#include <math.h>

#define NDEG 64          // N
#define LMAX 66          // N + 2
#define LDCB 67          // cBar/sBar row stride (N + 3)
#define NCOL 63          // columns m=0..62 have inner (l>=m+2) entries
#define TAB_F4 2112      // total packed float4 count = sum_m 4*ceil((63-m)/4)

#define MU_F   398600441800000.0f
#define AREF_F 6378136.3f

#define NSUB 8           // sub-waves per element group
#define EPW  64          // elements per wave (= wave size)

// 64-byte group of 4 packed constant entries (n1,n2,cBar,sBar)
struct Cons4 { float4 v[4]; };

// ---------------------------------------------------------------------------
// Setup, fully parallel: grid = 17 blocks x 256.
//  block 0, thread m (m<=64): heads + colstart
//    headA[m] = (diag[m], sub[m+1]*diag[m+1], cBar[m][m], sBar[m][m])
//    headB[m] = (cBar[m+1][m], sBar[m+1][m], 0, 0)
//    colstart[m] = packed float4 offset of column m
//  blocks 1..16, one thread per (m,i) in the 63x64 rectangle: one packed
//    triangle entry tab[colstart(m)+i] = (n1,n2,cB,sB) (zero if i>=cnt pad).
//  Integer products < 2^24 are exact in fp32; sqrtf is 1-ulp.
// ---------------------------------------------------------------------------
__global__ void pines_setup(const float* __restrict__ cBar,
                            const float* __restrict__ sBar,
                            float4* __restrict__ tab,
                            float4* __restrict__ headA,
                            float4* __restrict__ headB,
                            int*    __restrict__ colstart) {
    int t = threadIdx.x;
    if (blockIdx.x == 0) {
        if (t <= NDEG) {
            int m = t;
            double d = 1.0;
            for (int l = 1; l <= m; ++l) {
                double kp = (l == 1) ? 1.0 : 2.0;
                d *= sqrt((2.0 * l + 1.0) * 2.0 / (2.0 * l * kp));
            }
            double fnext;
            {
                int l = m + 1;
                double kp = (l == 1) ? 1.0 : 2.0;
                fnext = sqrt((2.0 * l + 1.0) * 2.0 / (2.0 * l * kp));
            }
            double diag1 = d * fnext;                                  // diag[m+1]
            double sub1  = sqrt((double)(m + 1) * ((m == 0) ? 1.0 : 2.0)); // sub[m+1]
            headA[m] = make_float4((float)d, (float)(sub1 * diag1),
                                   cBar[m * LDCB + m], sBar[m * LDCB + m]);
            float cb1 = (m < NDEG) ? cBar[(m + 1) * LDCB + m] : 0.0f;
            float sb1 = (m < NDEG) ? sBar[(m + 1) * LDCB + m] : 0.0f;
            headB[m] = make_float4(cb1, sb1, 0.0f, 0.0f);
            int off = 0;
            for (int mm = 0; mm < m && mm < NCOL; ++mm)
                off += ((63 - mm + 3) >> 2) << 2;
            colstart[m] = off;                                // m>=63 -> TAB_F4
        }
    } else {
        int idx = (blockIdx.x - 1) * blockDim.x + t;          // 0..4095
        if (idx < NCOL * 64) {
            int m = idx >> 6, i = idx & 63;
            int cnt = 63 - m;
            int pad = ((cnt + 3) >> 2) << 2;
            if (i < pad) {
                int off = 0;
                for (int mm = 0; mm < m; ++mm)
                    off += ((63 - mm + 3) >> 2) << 2;
                float4 v = make_float4(0.0f, 0.0f, 0.0f, 0.0f);
                if (i < cnt) {
                    int l = m + 2 + i;
                    float d1f = (float)((l - m) * (l + m));
                    float v1  = sqrtf((float)((2 * l + 1) * (2 * l - 1)) / d1f);
                    float d2f = (float)((l + m) * (l - m) * (2 * l - 3));
                    float n2f = (float)((l + m - 1) * (2 * l + 1) * (l - m - 1));
                    float v2  = sqrtf(n2f / d2f);
                    v = make_float4(v1, v2, cBar[l * LDCB + m], sBar[l * LDCB + m]);
                }
                tab[off + i] = v;
            }
        }
    }
}

// ---------------------------------------------------------------------------
// Main kernel. Block = 512 = 8 waves; wave w = sub index j, lanes = 64
// elements. Heads/colstart read via SGPR (s_load, prefetched one full
// column ahead). The 64 B Cons4 group loads are issued on the VECTOR
// memory pipe at a uniform address (offset laundered through v_mov_b32 so
// the compiler cannot re-scalarize): VMEM returns in-order and is tracked
// by vmcnt(N), so the depth-2 rotating buffers (c0/c1/c2) get ~2 iterations
// (~100+ cyc) of latency cover with partial waits — impossible with SMEM,
// whose OOO returns force lgkmcnt(0) drains. All lanes load the same
// address -> coalesced to one L1 transaction + broadcast.
// Zigzag: sub j owns m = j,15-j,16+j,31-j,32+j,47-j,48+j,63-j; 64 padded
// groups each -> perfect balance. Recursion rho-scaled:
//   q_l = rho^l*aBar[l][m];  q = (u*rho)*(n1*q1) - rho^2*(n2*q0)
// mu/r factored into the final store; zero-pad entries are inert.
// Buffer over-reads past a column's groups land in tab/heads inside ws —
// mapped, never consumed.
// ---------------------------------------------------------------------------
__global__ __launch_bounds__(512, 8) void pines_kernel(
        const float4* __restrict__ inputs,
        const float4* __restrict__ tab,
        const float4* __restrict__ headA,
        const float4* __restrict__ headB,
        const int*    __restrict__ colstart,
        float* __restrict__ out, int B) {
    __shared__ float part[NSUB][EPW];

    int t = threadIdx.x;
    int j = __builtin_amdgcn_readfirstlane(t >> 6);
    int e = t & (EPW - 1);
    int elem = blockIdx.x * EPW + e;
    int lelem = elem < B ? elem : (B - 1);

    float4 in = inputs[lelem];
    float r = in.x, ss = in.y, tt = in.z, u = in.w;

    float rho  = AREF_F / r;
    float rho2 = rho * rho;
    float ur   = u * rho;

    int d1 = 15 - 2 * j;
    int d2 = 1 + 2 * j;

    auto cpow = [&](int e_, float& re_, float& im_) {
        float br = ss, bi = tt;
        re_ = 1.0f; im_ = 0.0f;
        int ee = e_;
        while (ee) {
            if (ee & 1) {
                float nr = re_ * br - im_ * bi;
                im_ = re_ * bi + im_ * br;
                re_ = nr;
            }
            float sr = br * br - bi * bi;
            bi = 2.0f * br * bi;
            br = sr;
            ee >>= 1;
        }
    };
    auto rpow = [&](int e_) {
        float b = rho, acc = 1.0f;
        int ee = e_;
        while (ee) {
            if (ee & 1) acc *= b;
            b *= b;
            ee >>= 1;
        }
        return acc;
    };

    float re, im;      cpow(j, re, im);
    float s1r, s1i;    cpow(d1, s1r, s1i);
    float s2r, s2i;    cpow(d2, s2r, s2i);
    float rstep1 = rpow(d1);
    float rstep2 = rpow(d2);
    float rho_m  = rpow(j);              // rho^m at m = j

    float sum = (j == 0) ? 1.0f : 0.0f;  // l = 0 term (times mu/r at end)

    // zigzag m-sequence (wave-uniform)
    int ms[9];
    ms[0] = j;
    #pragma unroll
    for (int k = 0; k < 8; ++k) ms[k + 1] = ms[k] + ((k & 1) ? d2 : d1);

    int sm = __builtin_amdgcn_readfirstlane(ms[0]);
    float4 ha = headA[sm];
    float4 hb = headB[sm];
    int scol  = __builtin_amdgcn_readfirstlane(colstart[sm]);

    #pragma unroll 1
    for (int k = 0; k < 8; ++k) {
        // prefetch next column's heads + start (SMEM; a full column of cover)
        int smn = ms[k + 1] > 64 ? 64 : ms[k + 1];
        smn = __builtin_amdgcn_readfirstlane(smn);
        float4 ha_n = headA[smn];
        float4 hb_n = headB[smn];
        int scol_n  = __builtin_amdgcn_readfirstlane(colstart[smn]);

        float q0 = ha.x * rho_m;                       // q at l = m
        float sA = (sm >= 1) ? q0 * ha.z : 0.0f;
        float sB = (sm >= 1) ? q0 * ha.w : 0.0f;
        float q1 = (ha.y * u) * (rho_m * rho);         // q at l = m+1
        sA = fmaf(q1, hb.x, sA);
        sB = fmaf(q1, hb.y, sB);

        int ng = __builtin_amdgcn_readfirstlane((63 - sm + 3) >> 2);

        // launder the uniform offset into a VGPR so group loads go VMEM
        int vcol;
        asm("v_mov_b32 %0, %1" : "=v"(vcol) : "s"(scol));
        const Cons4* __restrict__ gp = (const Cons4*)(tab + vcol);

        Cons4 c0 = gp[0];
        Cons4 c1 = gp[1];
        #pragma unroll 1
        for (int g = 0; g < ng; ++g) {
            Cons4 c2 = gp[g + 2];                      // depth-2 prefetch
            #pragma unroll
            for (int q4 = 0; q4 < 4; ++q4) {
                float4 cc = c0.v[q4];
                float t1 = cc.x * q1;
                float t2 = ur * t1;
                float t3 = cc.y * q0;
                float q  = fmaf(-rho2, t3, t2);
                sA = fmaf(q, cc.z, sA);
                sB = fmaf(q, cc.w, sB);
                q0 = q1;
                q1 = q;
            }
            c0 = c1;
            c1 = c2;
        }
        sum = fmaf(re, sA, sum);
        sum = fmaf(im, sB, sum);

        // zigzag advance: even k -> +d1, odd k -> +d2
        if (k & 1) {
            float nr = re * s2r - im * s2i;
            im = re * s2i + im * s2r; re = nr;
            rho_m *= rstep2;
        } else {
            float nr = re * s1r - im * s1i;
            im = re * s1i + im * s1r; re = nr;
            rho_m *= rstep1;
        }
        sm = smn; ha = ha_n; hb = hb_n; scol = scol_n;
    }
    // sub 0 lands on m = 64: diagonal-only column (ha == headA[64] here)
    if (j == 0) {
        float q0 = ha.x * rho_m;
        sum = fmaf(re * q0, ha.z, sum);
        sum = fmaf(im * q0, ha.w, sum);
    }

    part[j][e] = sum;
    __syncthreads();
    if (j == 0) {
        float tot = 0.0f;
        #pragma unroll
        for (int q = 0; q < NSUB; ++q) tot += part[q][e];
        if (elem < B) out[elem] = -(MU_F / r) * tot;
    }
}

extern "C" void kernel_launch(void* const* d_in, const int* in_sizes, int n_in,
                              void* d_out, int out_size, void* d_ws, size_t ws_size,
                              hipStream_t stream) {
    const float* inputs = (const float*)d_in[0];   // (B, 4)
    const float* cBar   = (const float*)d_in[1];   // (67, 67)
    const float* sBar   = (const float*)d_in[2];   // (67, 67)
    float* out = (float*)d_out;
    int B = in_sizes[0] / 4;

    float4* tab   = (float4*)d_ws;                 // TAB_F4 float4 = 33,792 B
    float4* headA = tab + TAB_F4;                  // 65 float4
    float4* headB = headA + 65;
    int*    colst = (int*)(headB + 65);            // 65 ints

    hipLaunchKernelGGL(pines_setup, dim3(17), dim3(256), 0, stream,
                       cBar, sBar, tab, headA, headB, colst);

    int blocks = (B + EPW - 1) / EPW;
    hipLaunchKernelGGL(pines_kernel, dim3(blocks), dim3(512), 0, stream,
                       (const float4*)inputs, tab, headA, headB, colst,
                       out, B);
}

// Round 8
// 98.355 us; speedup vs baseline: 1.2957x; 1.2957x over previous
//
#include <hip/hip_runtime.h>
#include <math.h>

#define NDEG 64          // N
#define LDCB 67          // cBar/sBar row stride (N + 3)

#define MU_F   398600441800000.0f
#define AREF_F 6378136.3f

#define NSUB 8           // sub-waves per element group
#define EPW  64          // elements per wave (= wave size)
#define SGRP 72          // Cons4 groups per stream (fixed stride; max used = 72)
#define NREC 9           // head records per j (8 columns + m=64 tail)

// 64 B group of 4 packed entries (ntilde2, ctilde, stilde, pad)
struct Cons4 { float4 v[4]; };

__device__ __forceinline__ double n1d(int l, int m) {
    return sqrt((2.0 * l + 1.0) * (2.0 * l - 1.0) / ((double)(l - m) * (l + m)));
}
__device__ __forceinline__ double n2d(int l, int m) {
    return sqrt(((double)(l + m - 1) * (2 * l + 1) * (l - m - 1)) /
                ((double)(l + m) * (l - m) * (2 * l - 3)));
}

// ---------------------------------------------------------------------------
// Setup: grid 10 x 256, one thread per stream entry / head record.
// Stream j = concatenation over its zigzag columns (m = j, 15-j, 16+j, 31-j,
// 32+j, 47-j, 48+j, 63-j) of per-l entries, each column padded to a multiple
// of 8 entries (one 128 B trip = 2 Cons4 groups). Entry (fused/rescaled):
//   ntilde2 = n2[l]/(n1[l]*n1[l-1])   (n1[m+1] := 1)
//   ctilde  = cBar[l][m] * ghat_l,  stilde = sBar[l][m] * ghat_l
//   ghat_l  = prod_{t=m+2..l} n1[t][m]
// so the kernel recursion is q^ = fma(ur, q1, -rho2*(ntilde2*q0)) with the
// contribution ctilde*q^ == cBar*q exactly (magnitudes preserved).
// Head record (j,k) 32 B: (diag[m], sub[m+1]*diag[m+1], cB[m][m]|0, sB[m][m]|0,
//                          cB[m+1][m]|0, sB[m+1][m]|0, 0, 0); record 8 is the
// m=64 diagonal (j=0 only; zeros otherwise -> branchless tail).
// ---------------------------------------------------------------------------
__global__ void pines_setup(const float* __restrict__ cBar,
                            const float* __restrict__ sBar,
                            float4* __restrict__ stream,   // 8*SGRP*4 float4
                            float4* __restrict__ hrec) {   // 8*NREC*2 float4
    int tid = blockIdx.x * blockDim.x + threadIdx.x;
    if (tid < 8 * SGRP * 4) {
        int j = tid / (SGRP * 4);
        int rem = tid % (SGRP * 4);
        int d1 = 15 - 2 * j, d2 = 1 + 2 * j;
        int m = j, base = 0, idx = -1;
        for (int k = 0; k < 8; ++k) {
            int len  = 63 - m;
            int ecap = ((len + 7) >> 3) << 3;    // padded entries this column
            if (rem < base + ecap) { idx = rem - base; break; }
            base += ecap;
            m += (k & 1) ? d2 : d1;
        }
        float4 v = make_float4(0.0f, 0.0f, 0.0f, 0.0f);
        if (idx >= 0) {
            int l = m + 2 + idx;
            if (l <= NDEG) {
                double g = 1.0;
                for (int t2 = m + 2; t2 <= l; ++t2) g *= n1d(t2, m);
                double nn1   = n1d(l, m);
                double nprev = (l - 1 >= m + 2) ? n1d(l - 1, m) : 1.0;
                double nt2   = n2d(l, m) / (nn1 * nprev);
                v = make_float4((float)nt2,
                                (float)(g * (double)cBar[l * LDCB + m]),
                                (float)(g * (double)sBar[l * LDCB + m]),
                                0.0f);
            }
        }
        stream[tid] = v;
    } else {
        int h = tid - 8 * SGRP * 4;
        if (h < 8 * NREC) {
            int j = h / NREC, k = h % NREC;
            int d1 = 15 - 2 * j, d2 = 1 + 2 * j;
            int m = j;
            for (int kk = 0; kk < k; ++kk) m += (kk & 1) ? d2 : d1;
            float4 a = make_float4(0.0f, 0.0f, 0.0f, 0.0f);
            float4 b = make_float4(0.0f, 0.0f, 0.0f, 0.0f);
            if (m <= NDEG) {
                double diag = 1.0;
                for (int l = 1; l <= m; ++l) {
                    double kp = (l == 1) ? 1.0 : 2.0;   // k[l-1]
                    diag *= sqrt((2.0 * l + 1.0) * 2.0 / (2.0 * l * kp));
                }
                double sd = 0.0;
                if (m < NDEG) {
                    double kprev = (m == 0) ? 1.0 : 2.0;              // k[m]
                    double f    = sqrt((2.0 * (m + 1) + 1.0) * 2.0 /
                                       (2.0 * (m + 1) * kprev));      // f(m+1)
                    double sub1 = sqrt((double)(m + 1) * kprev);      // sub[m+1]
                    sd = sub1 * diag * f;                             // sub*diag[m+1]
                }
                float cmm = (m >= 1) ? cBar[m * LDCB + m] : 0.0f;
                float smm = (m >= 1) ? sBar[m * LDCB + m] : 0.0f;
                float cb1 = (m < NDEG) ? cBar[(m + 1) * LDCB + m] : 0.0f;
                float sb1 = (m < NDEG) ? sBar[(m + 1) * LDCB + m] : 0.0f;
                a = make_float4((float)diag, (float)sd, cmm, smm);
                b = make_float4(cb1, sb1, 0.0f, 0.0f);
            }
            hrec[h * 2]     = a;
            hrec[h * 2 + 1] = b;
        }
    }
}

// ---------------------------------------------------------------------------
// Main kernel. Block = 512 = 8 waves; wave j, lanes = 64 elements. Each wave
// streams its private linear coefficient stream via SMEM (s_load_dwordx16
// pairs, 128 B per trip = 8 inner iterations of 5 VALU each), so each
// lgkmcnt drain is covered by ~80 cycles of compute and drains/wave drop to
// ~36 + 8 head loads. Heads prefetched one column ahead. Recursion
// (fused/rescaled): q^ = fma(ur, q1, -rho2*(ntilde2*q0)); contributions via
// ctilde/stilde; mu/r factored into the final store. Pad entries (all-zero)
// are inert: q decays as (ur)^k, coefficients are 0.
// ---------------------------------------------------------------------------
__global__ __launch_bounds__(512, 8) void pines_kernel(
        const float4* __restrict__ inputs,
        const float4* __restrict__ stream,
        const float4* __restrict__ hrec,
        float* __restrict__ out, int B) {
    __shared__ float part[NSUB][EPW];

    int t = threadIdx.x;
    int j = __builtin_amdgcn_readfirstlane(t >> 6);
    int e = t & (EPW - 1);
    int elem = blockIdx.x * EPW + e;
    int lelem = elem < B ? elem : (B - 1);

    float4 in = inputs[lelem];
    float r = in.x, ss = in.y, tt = in.z, u = in.w;

    float rho   = AREF_F / r;
    float rho2  = rho * rho;
    float nrho2 = -rho2;
    float ur    = u * rho;

    int d1 = 15 - 2 * j;
    int d2 = 1 + 2 * j;

    auto cpow = [&](int e_, float& re_, float& im_) {
        float br = ss, bi = tt;
        re_ = 1.0f; im_ = 0.0f;
        int ee = e_;
        while (ee) {
            if (ee & 1) {
                float nr = re_ * br - im_ * bi;
                im_ = re_ * bi + im_ * br;
                re_ = nr;
            }
            float sr = br * br - bi * bi;
            bi = 2.0f * br * bi;
            br = sr;
            ee >>= 1;
        }
    };
    auto rpow = [&](int e_) {
        float b = rho, acc = 1.0f;
        int ee = e_;
        while (ee) {
            if (ee & 1) acc *= b;
            b *= b;
            ee >>= 1;
        }
        return acc;
    };

    float re, im;      cpow(j, re, im);
    float s1r, s1i;    cpow(d1, s1r, s1i);
    float s2r, s2i;    cpow(d2, s2r, s2i);
    float rstep1 = rpow(d1);
    float rstep2 = rpow(d2);
    float rho_m  = rpow(j);              // rho^m at m = j

    float sum = (j == 0) ? 1.0f : 0.0f;  // l = 0 term (times mu/r at end)

    const float4* __restrict__ hp = hrec + j * NREC * 2;
    const Cons4*  __restrict__ sp = (const Cons4*)stream + j * SGRP;

    float4 h0 = hp[0];
    float4 h1 = hp[1];

    int m = j, g = 0;
    #pragma unroll 1
    for (int k = 0; k < 8; ++k) {
        int sm = __builtin_amdgcn_readfirstlane(m);
        // prefetch next column's head record (record 8 for k==7: m=64 tail)
        float4 h0n = hp[2 * k + 2];
        float4 h1n = hp[2 * k + 3];

        float q0 = h0.x * rho_m;                       // q at l = m
        float sA = q0 * h0.z;                          // cB[m][m] (0 for m=0)
        float sB = q0 * h0.w;
        float q1 = (h0.y * u) * (rho_m * rho);         // q at l = m+1
        sA = fmaf(q1, h1.x, sA);
        sB = fmaf(q1, h1.y, sB);

        int ntr = __builtin_amdgcn_readfirstlane((63 - sm + 7) >> 3);
        #pragma unroll 1
        for (int tr = 0; tr < ntr; ++tr) {
            Cons4 ca = sp[g];                          // s_load_dwordx16
            Cons4 cb = sp[g + 1];                      // s_load_dwordx16
            g += 2;
            #pragma unroll
            for (int q4 = 0; q4 < 4; ++q4) {
                float4 cc = ca.v[q4];
                float t3 = cc.x * q0;
                float t4 = nrho2 * t3;
                float q  = fmaf(ur, q1, t4);
                sA = fmaf(q, cc.y, sA);
                sB = fmaf(q, cc.z, sB);
                q0 = q1; q1 = q;
            }
            #pragma unroll
            for (int q4 = 0; q4 < 4; ++q4) {
                float4 cc = cb.v[q4];
                float t3 = cc.x * q0;
                float t4 = nrho2 * t3;
                float q  = fmaf(ur, q1, t4);
                sA = fmaf(q, cc.y, sA);
                sB = fmaf(q, cc.z, sB);
                q0 = q1; q1 = q;
            }
        }
        sum = fmaf(re, sA, sum);
        sum = fmaf(im, sB, sum);

        // zigzag advance: even k -> +d1, odd k -> +d2
        if (k & 1) {
            float nr = re * s2r - im * s2i;
            im = re * s2i + im * s2r; re = nr;
            rho_m *= rstep2; m += d2;
        } else {
            float nr = re * s1r - im * s1i;
            im = re * s1i + im * s1r; re = nr;
            rho_m *= rstep1; m += d1;
        }
        h0 = h0n; h1 = h1n;
    }
    // m=64 diagonal tail: h0 == record 8 (zeros unless j==0) -> branchless
    {
        float q0 = h0.x * rho_m;
        sum = fmaf(re * q0, h0.z, sum);
        sum = fmaf(im * q0, h0.w, sum);
    }

    part[j][e] = sum;
    __syncthreads();
    if (j == 0) {
        float tot = 0.0f;
        #pragma unroll
        for (int q = 0; q < NSUB; ++q) tot += part[q][e];
        if (elem < B) out[elem] = -(MU_F / r) * tot;
    }
}

extern "C" void kernel_launch(void* const* d_in, const int* in_sizes, int n_in,
                              void* d_out, int out_size, void* d_ws, size_t ws_size,
                              hipStream_t stream_h) {
    const float* inputs = (const float*)d_in[0];   // (B, 4)
    const float* cBar   = (const float*)d_in[1];   // (67, 67)
    const float* sBar   = (const float*)d_in[2];   // (67, 67)
    float* out = (float*)d_out;
    int B = in_sizes[0] / 4;

    float4* strm = (float4*)d_ws;                  // 8*SGRP*4 = 2304 float4
    float4* hrec = strm + 8 * SGRP * 4;            // 8*NREC*2 = 144 float4

    hipLaunchKernelGGL(pines_setup, dim3(10), dim3(256), 0, stream_h,
                       cBar, sBar, strm, hrec);

    int blocks = (B + EPW - 1) / EPW;
    hipLaunchKernelGGL(pines_kernel, dim3(blocks), dim3(512), 0, stream_h,
                       (const float4*)inputs, strm, hrec, out, B);
}